// Round 4
// baseline (226.722 us; speedup 1.0000x reference)
//
#include <hip/hip_runtime.h>
#include <hip/hip_bf16.h>

typedef __bf16 bf16x8 __attribute__((ext_vector_type(8)));
typedef float f32x4 __attribute__((ext_vector_type(4)));

#define LAT 512

__device__ __forceinline__ void async_load16(const void* g, void* l) {
  __builtin_amdgcn_global_load_lds(
      (const __attribute__((address_space(1))) unsigned int*)g,
      (__attribute__((address_space(3))) unsigned int*)l, 16, 0, 0);
}

// ---------------- kernel 1: style affine  s[b][cin] = style[b]@style_w[:,cin] + style_b[cin]
__global__ void style_kernel(const float* __restrict__ style,
                             const float* __restrict__ style_w,
                             const float* __restrict__ style_b,
                             float* __restrict__ smod) {
  int b = blockIdx.x, cin = threadIdx.x;
  float acc = style_b[cin];
  const float* st = style + b * LAT;
  for (int l = 0; l < LAT; ++l)
    acc = fmaf(st[l], style_w[l * 256 + cin], acc);
  smod[b * 256 + cin] = acc;
}

// ---------------- kernel 2: modulate + demodulate -> bf16 wmod[b][tap][cout][cin]
__global__ void modw_kernel(const float* __restrict__ weight,
                            const float* __restrict__ smod,
                            __hip_bfloat16* __restrict__ wmod) {
  int cout = blockIdx.x, b = blockIdx.y;
  int cin = threadIdx.x;
  float s = smod[b * 256 + cin];
  const float* wp = weight + ((size_t)cout * 256 + cin) * 9;
  float w[9];
  float ss = 0.f;
#pragma unroll
  for (int j = 0; j < 9; ++j) { w[j] = wp[j]; ss = fmaf(w[j], w[j], ss); }
  ss *= s * s;
#pragma unroll
  for (int off = 32; off > 0; off >>= 1) ss += __shfl_down(ss, off, 64);
  __shared__ float red[4];
  __shared__ float dsh;
  int lane = threadIdx.x & 63, wv = threadIdx.x >> 6;
  if (lane == 0) red[wv] = ss;
  __syncthreads();
  if (threadIdx.x == 0) dsh = rsqrtf(red[0] + red[1] + red[2] + red[3] + 1e-8f);
  __syncthreads();
  float d = dsh * s;
  size_t obase = ((size_t)(b * 9) * 256 + cout) * 256 + cin;
#pragma unroll
  for (int j = 0; j < 9; ++j)
    wmod[obase + (size_t)j * 65536] = __float2bfloat16(w[j] * d);
}

// ---------------- kernel 3: zero the pad border of x_t[b][66][66][256]
__global__ void border_kernel(__hip_bfloat16* __restrict__ xt) {
  int bp = blockIdx.x;  // 0..259
  int b = blockIdx.y;
  int h, w;
  if (bp < 66)       { h = 0;        w = bp; }
  else if (bp < 132) { h = 65;       w = bp - 66; }
  else if (bp < 196) { h = bp - 131; w = 0; }
  else               { h = bp - 195; w = 65; }
  xt[((size_t)(b * 66 + h) * 66 + w) * 256 + threadIdx.x] = __float2bfloat16(0.f);
}

// ---------------- kernel 4: NCHW fp32 -> padded NHWC bf16
__global__ void transpose_kernel(const float* __restrict__ x,
                                 __hip_bfloat16* __restrict__ xt) {
  __shared__ __hip_bfloat16 tile[64][258];
  int h = blockIdx.x, b = blockIdx.y, t = threadIdx.x;
  int w4 = (t & 15) * 4;
  int csub = t >> 4;  // 0..15
  for (int c0 = 0; c0 < 256; c0 += 16) {
    int cin = c0 + csub;
    const float4 v = *(const float4*)(x + (((size_t)(b * 256 + cin) * 64 + h) << 6) + w4);
    tile[w4 + 0][cin] = __float2bfloat16(v.x);
    tile[w4 + 1][cin] = __float2bfloat16(v.y);
    tile[w4 + 2][cin] = __float2bfloat16(v.z);
    tile[w4 + 3][cin] = __float2bfloat16(v.w);
  }
  __syncthreads();
  int wsub = t >> 7;    // 0..1
  int cpair = t & 127;  // 0..127
  size_t obase = ((size_t)(b * 66 + h + 1) * 66 + 1) * 256;
  for (int w0 = 0; w0 < 64; w0 += 2) {
    int w = w0 + wsub;
    unsigned int v = *(const unsigned int*)&tile[w][cpair * 2];
    *(unsigned int*)((__hip_bfloat16*)xt + obase + (size_t)w * 256 + cpair * 2) = v;
  }
}

// ---------------- kernel 5: implicit-GEMM conv + noise + bias + lrelu*sqrt2
// Block: 128 cout x 256 spatial (4 output rows), 4 waves, wave tile 64x128.
// BISECT round: keep new geometry, revert to round-1-proven staging pattern:
// one (tap,kc32) B tile per step, fixed read offsets, uniform 72-step pipeline
// {vmcnt(6) -> barrier -> 32 MFMA -> barrier -> stage s+2}.  LDS 48KB.
// grid: (16 spatial, 2 cout, 16 batch) -> XCD-swizzled, 256 threads
__global__ __launch_bounds__(256, 2)
void conv_kernel(const __hip_bfloat16* __restrict__ wmod,
                 const __hip_bfloat16* __restrict__ xt,
                 const float* __restrict__ noise,
                 const float* __restrict__ bias,
                 const float* __restrict__ nwt,
                 float* __restrict__ out) {
  // A0 [0,8K) A1 [8K,16K) B0 [16K,32K) B1 [32K,48K)
  __shared__ __align__(16) char lds[49152];
  const int t = threadIdx.x;

  // ---- XCD-aware bijective swizzle: 512 blocks = 8 XCD x 64
  const int bid = blockIdx.x + (blockIdx.y << 4) + (blockIdx.z << 5);
  const int nid = ((bid & 7) << 6) + (bid >> 3);
  const int sp = nid & 15;                  // spatial tile: output rows 4sp..4sp+3
  const int cout0 = ((nid >> 4) & 1) << 7;  // 0 or 128
  const int b = nid >> 5;                   // batch

  const int lane = t & 63;
  const int wv = t >> 6;
  const int mw = (wv >> 1) << 6;   // 0 / 64   (cout within block)
  const int nwl = (wv & 1) << 7;   // 0 / 128  (spatial within block)
  const int col = lane & 15, quad = lane >> 4;

  // ---- A staging source offsets (pre-swizzled source, linear LDS dest)
  // A layout: chunk(m,k8) = m*4 + (k8 ^ ((m>>1)&3)); 4 x 16B chunks per cout row
  unsigned asrc[2];
#pragma unroll
  for (int it = 0; it < 2; ++it) {
    int ch = it * 256 + t;
    int m = ch >> 2, qs = ch & 3;
    int k8 = qs ^ ((m >> 1) & 3);
    asrc[it] = (unsigned)((cout0 + m) * 256 + k8 * 8);
  }
  const size_t wbase = (size_t)b * 9 * 65536;

  // ---- B staging source offsets: per (tap,kc) tile of 256 output positions.
  // B layout: chunk(n,k8) = n*4 + (k8 ^ ((n>>1)&3)); n = local output pos 0..255.
  // Source for n at tap (kh,kw): xt[b][4sp + (n>>6) + kh][(n&63) + kw][cin]
  // = base0 + (dtap<<8) + kc*32, dtap = kh*66+kw.
  unsigned bsrc0[4];
#pragma unroll
  for (int it = 0; it < 4; ++it) {
    int ch = it * 256 + t;
    int n = ch >> 2, qs = ch & 3;
    int k8 = qs ^ ((n >> 1) & 3);
    bsrc0[it] = (unsigned)((((b * 66 + (sp << 2) + (n >> 6)) * 66 + (n & 63)) << 8) + k8 * 8);
  }

  // ---- fragment LDS byte offsets (within buffer)
  int aro[4];
#pragma unroll
  for (int i = 0; i < 4; ++i) {
    int m = mw + i * 16 + col;
    aro[i] = (m << 6) + ((quad ^ ((m >> 1) & 3)) << 4);
  }
  int bro[8];
#pragma unroll
  for (int j = 0; j < 8; ++j) {
    int n = nwl + j * 16 + col;
    bro[j] = (n << 6) + ((quad ^ ((n >> 1) & 3)) << 4);
  }

  f32x4 acc[4][8];
#pragma unroll
  for (int i = 0; i < 4; ++i)
#pragma unroll
    for (int j = 0; j < 8; ++j)
      acc[i][j] = (f32x4){0.f, 0.f, 0.f, 0.f};

  // stage step (kc,tap) -> buf: A 2 loads + B 4 loads = 6 VMEM per wave
  auto stage = [&](int kc, int tap, int buf) {
    const int dtap = (tap / 3) * 66 + (tap % 3);
    const __hip_bfloat16* asrcp = wmod + wbase + tap * 65536 + kc * 32;
    const __hip_bfloat16* bsrcp = xt + (dtap << 8) + kc * 32;
    char* adst = lds + buf * 8192 + t * 16;
    char* bdst = lds + 16384 + buf * 16384 + t * 16;
    async_load16(asrcp + asrc[0], adst);
    async_load16(asrcp + asrc[1], adst + 4096);
#pragma unroll
    for (int it = 0; it < 4; ++it)
      async_load16(bsrcp + bsrc0[it], bdst + it * 4096);
  };

  auto compute = [&](int buf) {
    const char* A = lds + buf * 8192;
    const char* Bb = lds + 16384 + buf * 16384;
    bf16x8 af[4], bfr[8];
#pragma unroll
    for (int i = 0; i < 4; ++i) af[i] = *(const bf16x8*)(A + aro[i]);
#pragma unroll
    for (int j = 0; j < 8; ++j) bfr[j] = *(const bf16x8*)(Bb + bro[j]);
#pragma unroll
    for (int i = 0; i < 4; ++i)
#pragma unroll
      for (int j = 0; j < 8; ++j)
        acc[i][j] = __builtin_amdgcn_mfma_f32_16x16x32_bf16(af[i], bfr[j], acc[i][j], 0, 0, 0);
  };

  // prologue: stage steps 0 and 1 (12 loads in flight)
  stage(0, 0, 0);
  __builtin_amdgcn_sched_barrier(0);
  stage(0, 1, 1);
  __builtin_amdgcn_sched_barrier(0);

#pragma unroll
  for (int kc = 0; kc < 8; ++kc) {
#pragma unroll
    for (int tap = 0; tap < 9; ++tap) {
      const int s = kc * 9 + tap;
      // FIFO at top: [stage s (6), stage s+1 (6)] -> vmcnt(6) drains stage s.
      if (s == 71) asm volatile("s_waitcnt vmcnt(0)" ::: "memory");
      else         asm volatile("s_waitcnt vmcnt(6)" ::: "memory");
      __builtin_amdgcn_s_barrier();
      __builtin_amdgcn_sched_barrier(0);
      __builtin_amdgcn_s_setprio(1);
      compute(s & 1);
      __builtin_amdgcn_s_setprio(0);
      __builtin_amdgcn_s_barrier();
      __builtin_amdgcn_sched_barrier(0);
      if (s <= 69) {
        const int s2 = s + 2;
        stage(s2 / 9, s2 % 9, s & 1);  // s2 has same parity as s
        __builtin_amdgcn_sched_barrier(0);
      }
    }
  }

  // epilogue: D[m][n]: lane reg r -> m = quad*4+r, n = col (m89/m91 layout)
  const float nw0 = nwt[0];
  float nz[8];
#pragma unroll
  for (int j = 0; j < 8; ++j)
    nz[j] = noise[(b << 12) + (sp << 8) + nwl + j * 16 + col] * nw0;
#pragma unroll
  for (int i = 0; i < 4; ++i) {
    const int mloc = mw + i * 16 + quad * 4;
    const float4 b4 = *(const float4*)(bias + cout0 + mloc);
#pragma unroll
    for (int j = 0; j < 8; ++j) {
      const int p = (sp << 8) + nwl + j * 16 + col;
      f32x4 v = acc[i][j];
      const float bb[4] = {b4.x, b4.y, b4.z, b4.w};
#pragma unroll
      for (int r = 0; r < 4; ++r) {
        const int coutg = cout0 + mloc + r;
        float val = v[r] + nz[j] + bb[r];
        val = (val > 0.f ? val : 0.2f * val) * 1.4142135623730951f;
        out[(((size_t)(b * 256 + coutg)) << 12) + p] = val;
      }
    }
  }
}

extern "C" void kernel_launch(void* const* d_in, const int* in_sizes, int n_in,
                              void* d_out, int out_size, void* d_ws, size_t ws_size,
                              hipStream_t stream) {
  const float* x        = (const float*)d_in[0];
  const float* style    = (const float*)d_in[1];
  const float* noise    = (const float*)d_in[2];
  const float* weight   = (const float*)d_in[3];
  const float* style_w  = (const float*)d_in[4];
  const float* style_b  = (const float*)d_in[5];
  const float* bias     = (const float*)d_in[6];
  const float* noise_w  = (const float*)d_in[7];
  float* out = (float*)d_out;

  char* ws = (char*)d_ws;
  float* smod = (float*)ws;                                    // 16 KB
  __hip_bfloat16* wmod = (__hip_bfloat16*)(ws + 16384);        // 18.87 MB
  __hip_bfloat16* xt = (__hip_bfloat16*)(ws + 16384 + 18874368);  // 35.68 MB

  style_kernel<<<16, 256, 0, stream>>>(style, style_w, style_b, smod);
  modw_kernel<<<dim3(256, 16), 256, 0, stream>>>(weight, smod, wmod);
  border_kernel<<<dim3(260, 16), 256, 0, stream>>>(xt);
  transpose_kernel<<<dim3(64, 16), 256, 0, stream>>>(x, xt);
  conv_kernel<<<dim3(16, 2, 16), 256, 0, stream>>>(wmod, xt, noise, bias, noise_w, out);
}